// Round 2
// baseline (316.390 us; speedup 1.0000x reference)
//
#include <hip/hip_runtime.h>

typedef __attribute__((ext_vector_type(8))) short short8;
typedef __attribute__((ext_vector_type(4))) float f32x4;
typedef unsigned short ushort_t;

#define DEV __device__ __forceinline__

DEV ushort_t f2bf(float f) {
    unsigned u = __builtin_bit_cast(unsigned, f);
    u = u + 0x7fffu + ((u >> 16) & 1u);   // RNE
    return (ushort_t)(u >> 16);
}

DEV short8 ld8(const ushort_t* p) { return *reinterpret_cast<const short8*>(p); }

// ---------------------------------------------------------------------------
// C[M=4096, N] = A[4096,1024] @ W[1024,N] + bias, output bf16.
// Q/K rows -> outRow as [b,h,s,64]; V half (n>=1024, when outT set) -> outT
// transposed [b,h,64,s] so attention reads V k-contiguous.
// ---------------------------------------------------------------------------
__global__ __launch_bounds__(256)
void proj_gemm(const float* __restrict__ A, const float* __restrict__ W,
               const float* __restrict__ bias, int N,
               ushort_t* __restrict__ outRow, ushort_t* __restrict__ outT)
{
    __shared__ ushort_t As[128 * 72];  // [row m 0..127][k 0..63], stride 72 (pad)
    __shared__ ushort_t Bt[128 * 72];  // [col n 0..127][k 0..63], stride 72

    const int t = threadIdx.x;
    const int lane = t & 63;
    const int wv = t >> 6;
    const int wr = wv >> 1, wc = wv & 1;
    const int c = lane & 15, g = lane >> 4;
    const int m0 = blockIdx.y * 128, n0 = blockIdx.x * 128;

    f32x4 acc[4][4];
    const f32x4 zero4 = {0.f, 0.f, 0.f, 0.f};
#pragma unroll
    for (int mi = 0; mi < 4; ++mi)
#pragma unroll
        for (int ni = 0; ni < 4; ++ni) acc[mi][ni] = zero4;

    for (int it = 0; it < 16; ++it) {
        const int k0 = it * 64;
        // stage A tile: 128 rows x 64 k (f32 -> bf16)
        {
            const int kq = (t & 15) * 4;
            int r = t >> 4;
#pragma unroll
            for (int rep = 0; rep < 8; ++rep, r += 16) {
                float4 v = *reinterpret_cast<const float4*>(
                    A + (size_t)(m0 + r) * 1024 + k0 + kq);
                ushort_t* dst = &As[r * 72 + kq];
                dst[0] = f2bf(v.x); dst[1] = f2bf(v.y);
                dst[2] = f2bf(v.z); dst[3] = f2bf(v.w);
            }
        }
        // stage W tile (64 k x 128 n), transposed into Bt[n][k]
        {
            const int nq = (t & 31) * 4;
            const int kr = t >> 5;
#pragma unroll
            for (int rep = 0; rep < 8; ++rep) {
                const int k = kr + 8 * rep;
                float4 v = *reinterpret_cast<const float4*>(
                    W + (size_t)(k0 + k) * N + n0 + nq);
                Bt[(nq + 0) * 72 + k] = f2bf(v.x);
                Bt[(nq + 1) * 72 + k] = f2bf(v.y);
                Bt[(nq + 2) * 72 + k] = f2bf(v.z);
                Bt[(nq + 3) * 72 + k] = f2bf(v.w);
            }
        }
        __syncthreads();
#pragma unroll
        for (int kk = 0; kk < 64; kk += 32) {
            short8 afr[4], bfr[4];
#pragma unroll
            for (int mi = 0; mi < 4; ++mi)
                afr[mi] = ld8(&As[(wr * 64 + mi * 16 + c) * 72 + kk + 8 * g]);
#pragma unroll
            for (int ni = 0; ni < 4; ++ni)
                bfr[ni] = ld8(&Bt[(wc * 64 + ni * 16 + c) * 72 + kk + 8 * g]);
#pragma unroll
            for (int mi = 0; mi < 4; ++mi)
#pragma unroll
                for (int ni = 0; ni < 4; ++ni)
                    acc[mi][ni] = __builtin_amdgcn_mfma_f32_16x16x32_bf16(
                        afr[mi], bfr[ni], acc[mi][ni], 0, 0, 0);
        }
        __syncthreads();
    }

    // epilogue: D row = 4*g + j (+16*mi +64*wr), col = c (+16*ni +64*wc)
#pragma unroll
    for (int mi = 0; mi < 4; ++mi) {
#pragma unroll
        for (int ni = 0; ni < 4; ++ni) {
            const int n = n0 + wc * 64 + ni * 16 + c;
            const float bb = bias[n];
#pragma unroll
            for (int j = 0; j < 4; ++j) {
                const int m = m0 + wr * 64 + mi * 16 + 4 * g + j;
                const int b = m >> 11, s = m & 2047;
                const ushort_t val = f2bf(acc[mi][ni][j] + bb);
                if (outT != nullptr && n >= 1024) {
                    const int np = n - 1024;
                    const int hh = np >> 6, d = np & 63;
                    outT[(size_t)((b * 16 + hh) * 64 + d) * 2048 + s] = val;
                } else {
                    const int hh = n >> 6, d = n & 63;
                    outRow[((size_t)((b * 16 + hh) * 2048 + s)) * 64 + d] = val;
                }
            }
        }
    }
}

// ---------------------------------------------------------------------------
// Flash attention per (b,h). 4 waves x 32 q-rows = 128 q-rows / block.
// Swapped QK^T: S^T = mfma(A=K_tile, B=Q) so lane's column c = q row.
// m-output uses rank-2 trick: m = (a0*Wmo0 + a1*Wmo1)/l + bmo.
// ---------------------------------------------------------------------------
__global__ __launch_bounds__(256)
void attn_kernel(const ushort_t* __restrict__ Qr, const ushort_t* __restrict__ Kr,
                 const ushort_t* __restrict__ Vt, const float* __restrict__ cr,
                 const float* __restrict__ Wmo, const float* __restrict__ bmo,
                 float* __restrict__ out)
{
    const int t = threadIdx.x;
    const int wv = t >> 6;
    const int lane = t & 63;
    const int c = lane & 15, g = lane >> 4;
    const int bh = blockIdx.y;
    const int b = bh >> 4, hh = bh & 15;
    const int qb = blockIdx.x * 128 + wv * 32;

    const ushort_t* Qh = Qr + (size_t)bh * (2048 * 64);
    const ushort_t* Kh = Kr + (size_t)bh * (2048 * 64);
    const ushort_t* Vh = Vt + (size_t)bh * (64 * 2048);
    const float*   crb = cr + (size_t)b * (2048 * 2);

    short8 bq[2][2];
#pragma unroll
    for (int qt = 0; qt < 2; ++qt)
#pragma unroll
        for (int st = 0; st < 2; ++st)
            bq[qt][st] = ld8(Qh + (size_t)(qb + qt * 16 + c) * 64 + st * 32 + 8 * g);

    f32x4 accv[2][4];
    const f32x4 zero4 = {0.f, 0.f, 0.f, 0.f};
#pragma unroll
    for (int qt = 0; qt < 2; ++qt)
#pragma unroll
        for (int dt = 0; dt < 4; ++dt) accv[qt][dt] = zero4;

    float mst[2] = {-__builtin_inff(), -__builtin_inff()};
    float lst[2] = {0.f, 0.f};
    float a0s[2] = {0.f, 0.f};
    float a1s[2] = {0.f, 0.f};

    for (int kvb = 0; kvb < 2048; kvb += 32) {
        short8 ka[2][2];
#pragma unroll
        for (int ct = 0; ct < 2; ++ct)
#pragma unroll
            for (int st = 0; st < 2; ++st)
                ka[ct][st] = ld8(Kh + (size_t)(kvb + ct * 16 + c) * 64 + st * 32 + 8 * g);
        short8 bv[4];
#pragma unroll
        for (int dt = 0; dt < 4; ++dt)
            bv[dt] = ld8(Vh + (size_t)(dt * 16 + c) * 2048 + kvb + 8 * g);
        float2 crv[2][4];
#pragma unroll
        for (int ct = 0; ct < 2; ++ct)
#pragma unroll
            for (int r = 0; r < 4; ++r)
                crv[ct][r] = *reinterpret_cast<const float2*>(
                    crb + (size_t)(kvb + ct * 16 + 4 * g + r) * 2);

#pragma unroll
        for (int qt = 0; qt < 2; ++qt) {
            f32x4 sc[2];
#pragma unroll
            for (int ct = 0; ct < 2; ++ct) {
                f32x4 z = zero4;
                z = __builtin_amdgcn_mfma_f32_16x16x32_bf16(ka[ct][0], bq[qt][0], z, 0, 0, 0);
                z = __builtin_amdgcn_mfma_f32_16x16x32_bf16(ka[ct][1], bq[qt][1], z, 0, 0, 0);
                sc[ct] = z;
            }
            // lane holds S^T[kv = kvb+16*ct+4*g+j][q = c]
            float p[2][4];
            float tmax = -__builtin_inff();
#pragma unroll
            for (int ct = 0; ct < 2; ++ct)
#pragma unroll
                for (int j = 0; j < 4; ++j) {
                    const float s = sc[ct][j] * 0.125f;
                    p[ct][j] = s;
                    tmax = fmaxf(tmax, s);
                }
            tmax = fmaxf(tmax, __shfl_xor(tmax, 16, 64));
            tmax = fmaxf(tmax, __shfl_xor(tmax, 32, 64));
            const float mnew = fmaxf(mst[qt], tmax);
            const float corr = __expf(mst[qt] - mnew);
            mst[qt] = mnew;
            float lc = 0.f, a0c = 0.f, a1c = 0.f;
#pragma unroll
            for (int ct = 0; ct < 2; ++ct)
#pragma unroll
                for (int j = 0; j < 4; ++j) {
                    const float e = __expf(p[ct][j] - mnew);
                    p[ct][j] = e;
                    lc += e;
                    a0c += e * crv[ct][j].x;
                    a1c += e * crv[ct][j].y;
                }
            lc  += __shfl_xor(lc, 16, 64);  lc  += __shfl_xor(lc, 32, 64);
            a0c += __shfl_xor(a0c, 16, 64); a0c += __shfl_xor(a0c, 32, 64);
            a1c += __shfl_xor(a1c, 16, 64); a1c += __shfl_xor(a1c, 32, 64);
            lst[qt] = lst[qt] * corr + lc;
            a0s[qt] = a0s[qt] * corr + a0c;
            a1s[qt] = a1s[qt] * corr + a1c;

            // pack P to bf16 pairs. Lane (c,g) holds, for q=c:
            //   pk{ct}{wd} = P[kv = 16*ct + 4*g + 2*wd + {0,1}]
            const unsigned pk00 = (unsigned)f2bf(p[0][0]) | ((unsigned)f2bf(p[0][1]) << 16);
            const unsigned pk01 = (unsigned)f2bf(p[0][2]) | ((unsigned)f2bf(p[0][3]) << 16);
            const unsigned pk10 = (unsigned)f2bf(p[1][0]) | ((unsigned)f2bf(p[1][1]) << 16);
            const unsigned pk11 = (unsigned)f2bf(p[1][2]) | ((unsigned)f2bf(p[1][3]) << 16);

            // Redistribute into PV A-fragment: lane (c,g) needs
            //   af[w] = (P[q=c][8g+2w], P[q=c][8g+2w+1]),  w = 0..3.
            // kv=8g+2w = 16*(g>>1) + 4*(2*(g&1)+(w>>1)) + 2*(w&1):
            //   src lane g' = 2*(g&1) + (w>>1); word (ct=g>>1, wd=w&1).
            // __shfl returns the SOURCE's variable, so fetch all 4 words from
            // both candidate source lanes, then select by ct=g>>1 locally.
            const int src_e = c + 16 * (2 * (g & 1));
            const int src_o = src_e + 16;
            const int A00 = __shfl((int)pk00, src_e, 64);
            const int A01 = __shfl((int)pk01, src_e, 64);
            const int A10 = __shfl((int)pk10, src_e, 64);
            const int A11 = __shfl((int)pk11, src_e, 64);
            const int B00 = __shfl((int)pk00, src_o, 64);
            const int B01 = __shfl((int)pk01, src_o, 64);
            const int B10 = __shfl((int)pk10, src_o, 64);
            const int B11 = __shfl((int)pk11, src_o, 64);
            const bool hi = (g >> 1) != 0;
            int4 afi;
            afi.x = hi ? A10 : A00;
            afi.y = hi ? A11 : A01;
            afi.z = hi ? B10 : B00;
            afi.w = hi ? B11 : B01;
            const short8 afv = __builtin_bit_cast(short8, afi);

            float corr_r[4];
#pragma unroll
            for (int j = 0; j < 4; ++j) corr_r[j] = __shfl(corr, 4 * g + j, 64);
#pragma unroll
            for (int dt = 0; dt < 4; ++dt) {
#pragma unroll
                for (int j = 0; j < 4; ++j) accv[qt][dt][j] *= corr_r[j];
                accv[qt][dt] = __builtin_amdgcn_mfma_f32_16x16x32_bf16(
                    afv, bv[dt], accv[qt][dt], 0, 0, 0);
            }
        }
    }

    // epilogue: accv[qt][dt] reg j -> q = qb+qt*16+4g+j, d = dt*16+c
#pragma unroll
    for (int qt = 0; qt < 2; ++qt) {
        float lr[4], a0r[4], a1r[4];
#pragma unroll
        for (int j = 0; j < 4; ++j) {
            lr[j]  = __shfl(lst[qt], 4 * g + j, 64);
            a0r[j] = __shfl(a0s[qt], 4 * g + j, 64);
            a1r[j] = __shfl(a1s[qt], 4 * g + j, 64);
        }
#pragma unroll
        for (int dt = 0; dt < 4; ++dt) {
            const int d = dt * 16 + c;
            const float w0 = Wmo[hh * 64 + d];
            const float w1 = Wmo[1024 + hh * 64 + d];
            const float bm = bmo[hh * 64 + d];
#pragma unroll
            for (int j = 0; j < 4; ++j) {
                const int srow = qb + qt * 16 + 4 * g + j;
                const float inv = 1.f / lr[j];
                const size_t oidx = ((size_t)(b * 2048 + srow)) * 1024 + hh * 64 + d;
                out[oidx] = accv[qt][dt][j] * inv;
                out[4194304 + oidx] = (a0r[j] * w0 + a1r[j] * w1) * inv + bm;
            }
        }
    }
}

// ---------------------------------------------------------------------------
extern "C" void kernel_launch(void* const* d_in, const int* in_sizes, int n_in,
                              void* d_out, int out_size, void* d_ws, size_t ws_size,
                              hipStream_t stream)
{
    const float* i1  = (const float*)d_in[0];
    const float* i2  = (const float*)d_in[1];
    const float* cr  = (const float*)d_in[2];
    const float* Wq  = (const float*)d_in[3];
    const float* bq  = (const float*)d_in[4];
    const float* Wkv = (const float*)d_in[5];
    const float* bkv = (const float*)d_in[6];
    const float* Wmo = (const float*)d_in[7];
    const float* bmo = (const float*)d_in[8];
    float* out = (float*)d_out;

    ushort_t* Qr = (ushort_t*)d_ws;          // [2,16,2048,64] bf16
    ushort_t* Kr = Qr + 4194304;             // [2,16,2048,64] bf16
    ushort_t* Vt = Kr + 4194304;             // [2,16,64,2048] bf16

    dim3 blk(256);
    proj_gemm<<<dim3(8, 32), blk, 0, stream>>>(i1, Wq, bq, 1024, Qr, nullptr);
    proj_gemm<<<dim3(16, 32), blk, 0, stream>>>(i2, Wkv, bkv, 2048, Kr, Vt);
    attn_kernel<<<dim3(16, 32), blk, 0, stream>>>(Qr, Kr, Vt, cr, Wmo, bmo, out);
}